// Round 1
// 552.879 us; speedup vs baseline: 1.1209x; 1.1209x over previous
//
#include <hip/hip_runtime.h>
#include <hip/hip_bf16.h>

typedef __hip_bfloat16 bf16;
typedef __attribute__((ext_vector_type(8))) short s8v;   // 8 bf16 = 4 VGPRs (MFMA A/B frag)
typedef __attribute__((ext_vector_type(4))) float f4v;   // MFMA C/D frag

#define B_  2
#define S_  2048
#define D_  2048
#define H_  16
#define HD_ 128
#define INV_NORM 0.08838834764831845f

static __device__ __forceinline__ f4v mfma16(s8v a, s8v b, f4v c) {
    return __builtin_amdgcn_mfma_f32_16x16x32_bf16(a, b, c, 0, 0, 0);
}

static __device__ __forceinline__ void gload_lds(const void* gp, void* lp) {
    __builtin_amdgcn_global_load_lds(
        (const __attribute__((address_space(1))) unsigned int*)gp,
        (__attribute__((address_space(3))) unsigned int*)lp, 16, 0, 0);
}

// fp32 -> bf16 elementwise convert, 4 elems/thread
__global__ __launch_bounds__(256)
void cvt_f32_bf16(const float* __restrict__ src, bf16* __restrict__ dst, int n4)
{
    int i = blockIdx.x * 256 + threadIdx.x;
    if (i < n4) {
        float4 f = ((const float4*)src)[i];
        union { ushort4 u4; bf16 h[4]; } p;
        p.h[0] = __float2bfloat16(f.x);
        p.h[1] = __float2bfloat16(f.y);
        p.h[2] = __float2bfloat16(f.z);
        p.h[3] = __float2bfloat16(f.w);
        ((ushort4*)dst)[i] = p.u4;
    }
}

// C[M,N] = A[M,K] @ B[N,K]^T + bias; MODE 0: scatter to Q/K/V^T (bf16);
// MODE 1: + residual -> fp32 out. Block: 256 thr (4 waves), tile 128x128, BK=32.
// m97 structure: global_load_lds width-16 staging, unpadded [128][32] LDS.
template <int MODE>
__global__ __launch_bounds__(256)
void gemm_bt(const bf16* __restrict__ A, const bf16* __restrict__ Bw,
             const float* __restrict__ bias, const float* __restrict__ resid,
             bf16* __restrict__ o0, bf16* __restrict__ o1, bf16* __restrict__ o2,
             float* __restrict__ of, int K)
{
    __shared__ __align__(16) bf16 Al[128][32];   // unpadded: lane-contiguous for lds-DMA
    __shared__ __align__(16) bf16 Bl[128][32];
    const int tid  = threadIdx.x;
    const int wave = tid >> 6, lane = tid & 63;
    const int col  = lane & 15, quad = lane >> 4;
    const int wm = (wave >> 1) << 6, wn = (wave & 1) << 6;
    const int bn = blockIdx.x, bm = blockIdx.y;
    const bf16* Ab = A  + (size_t)bm * 128 * K;
    const bf16* Bb = Bw + (size_t)bn * 128 * K;

    const f4v fzero = {0.f, 0.f, 0.f, 0.f};
    f4v acc[4][4];
#pragma unroll
    for (int i = 0; i < 4; i++)
#pragma unroll
        for (int j = 0; j < 4; j++) acc[i][j] = fzero;

    for (int k0 = 0; k0 < K; k0 += 32) {
        // stage A,B tiles: granule g covers row=g>>2, ko=(g&3)*8 ; LDS dest = base + g*16
#pragma unroll
        for (int p = 0; p < 2; p++) {
            const int g = p * 256 + tid;
            const int r = g >> 2, ko = (g & 3) << 3;
            gload_lds(Ab + (size_t)r * K + k0 + ko, (char*)&Al[0][0] + (size_t)g * 16);
            gload_lds(Bb + (size_t)r * K + k0 + ko, (char*)&Bl[0][0] + (size_t)g * 16);
        }
        __syncthreads();
        s8v af[4], bfr[4];
#pragma unroll
        for (int i = 0; i < 4; i++) af[i]  = *(const s8v*)&Al[wm + i * 16 + col][quad * 8];
#pragma unroll
        for (int j = 0; j < 4; j++) bfr[j] = *(const s8v*)&Bl[wn + j * 16 + col][quad * 8];
#pragma unroll
        for (int i = 0; i < 4; i++)
#pragma unroll
            for (int j = 0; j < 4; j++)
                acc[i][j] = mfma16(af[i], bfr[j], acc[i][j]);
        __syncthreads();
    }

    // Epilogue. C/D layout: row = quad*4+reg, col = lane&15 (HW-verified m89/m91).
    if (MODE == 0) {
        // 128-col block == exactly one (h,t): 6144 = 16h * 3t * 128hd
        const int t = bn % 3, h = bn / 3;
#pragma unroll
        for (int j = 0; j < 4; j++) {
            const int c = wn + j * 16 + col;                      // hd in [0,128)
            const float bv = bias[bn * 128 + c];
#pragma unroll
            for (int i = 0; i < 4; i++) {
                const int r  = (bm << 7) + wm + i * 16 + (quad << 2); // 4 consecutive rows
                const int bb = r >> 11, s = r & (S_ - 1);
                if (t == 2) {
                    // V^T[b,h, hd, s]: 4 consecutive s -> one 8B store
                    union { ushort4 u4; bf16 hh[4]; } pk;
#pragma unroll
                    for (int rg = 0; rg < 4; rg++)
                        pk.hh[rg] = __float2bfloat16(acc[i][j][rg] + bv);
                    *(ushort4*)(o2 + ((size_t)(bb * H_ + h) * HD_ + c) * S_ + s) = pk.u4;
                } else {
                    bf16* dst = (t == 0) ? o0 : o1;   // Q or K: [b,h,s,hd]
#pragma unroll
                    for (int rg = 0; rg < 4; rg++)
                        dst[((size_t)(bb * H_ + h) * S_ + (s + rg)) * HD_ + c] =
                            __float2bfloat16(acc[i][j][rg] + bv);
                }
            }
        }
    } else {
#pragma unroll
        for (int j = 0; j < 4; j++) {
            const int c = (bn << 7) + wn + j * 16 + col;
            const float bv = bias[c];
#pragma unroll
            for (int i = 0; i < 4; i++) {
                const int r = (bm << 7) + wm + i * 16 + (quad << 2);
#pragma unroll
                for (int rg = 0; rg < 4; rg++) {
                    const size_t idx = (size_t)(r + rg) * D_ + c;
                    of[idx] = acc[i][j][rg] + bv + resid[idx];
                }
            }
        }
    }
}

// Flash attention, transposed-score formulation.
// Block: 256 thr (4 waves), 64 q-rows (wave w -> rows q0+w*16). K-tiles of 64 keys
// staged in LDS, shared by all waves. S^T = K.Q^T (C: row=key, col=q) -> softmax
// reduction is 15 in-lane ops + 2 shfls. O accumulated as ctx^T = V^T.P^T.
// Q,K: [B,H,S,HD] bf16; V^T: [B,H,HD,S] bf16; ctx out bf16 [B,S,H*HD].
//
// R1 changes vs previous session-best:
//  - qb load-balance swizzle: same-CU blocks (ids mod 256) previously got
//    identical qb -> 128-iter critical path per hot CU; now alternate
//    {31-x, x} by (blockIdx.y>>3)&1 so every CU sums to exactly 66 iters.
//  - XOR-swizzled LINEAR LDS tiles (no pads): Kl 16K + Vl 16K + Pl 8K =
//    40960 B exactly -> 4 blocks/CU (was 45056 -> 3). Whole 1024-block grid
//    co-resident. Swizzle: byte ^= ((row&7)<<4) on 16B blocks; every b128
//    access lands 8 lanes per 16B bank-group = phase-optimal.
//  - T14 async-STAGE: K/V global loads for tile kt+1 issued into regs right
//    after the compute-enables barrier; regs->LDS at top of next iter. HBM
//    latency (~900 cyc, L2-thrashed) hides under MFMA+softmax.
//  - mid __syncthreads() after Pl write removed (Pl wave-private; lgkmcnt
//    orders ds_write->ds_read within the wave).
//  - T5 s_setprio(1) around MFMA clusters (m191: +4-7% on attn).
__global__ __launch_bounds__(256, 4)
void attn(const bf16* __restrict__ Qb, const bf16* __restrict__ Kb,
          const bf16* __restrict__ Vt, bf16* __restrict__ ctx)
{
    __shared__ __align__(16) char Kl[64 * 256];     // [key][hd=128 bf16], swizzled
    __shared__ __align__(16) char Vl[128 * 128];    // [hd][key=64 bf16], swizzled
    __shared__ __align__(16) char Pl[4 * 16 * 128]; // per-wave [q=16][key=64], swizzled

    const int x = blockIdx.x;
    const int bh = blockIdx.y;                             // 0..31
    const int u = (bh >> 3) & 1;
    const int qb = u ? x : (int)gridDim.x - 1 - x;         // per-CU balance: {31-x, x}
    const int b = bh >> 4, h = bh & 15;
    const int tid = threadIdx.x;
    const int wave = tid >> 6, lane = tid & 63;
    const int col = lane & 15, quad = lane >> 4;
    const int q0 = qb << 6;
    const int qg = q0 + wave * 16 + col;          // this lane's q row (global)
    const float slope = exp2f(-0.5f * (float)(h + 1));
    const int sw = (col & 7) << 4;                // fragment-read swizzle term

    // Q fragments (B-operand): n=q=col, k=quad*8+j (+32c)
    const bf16* Qp = Qb + ((size_t)bh * S_ + q0 + wave * 16) * HD_;
    s8v aq[4];
#pragma unroll
    for (int c = 0; c < 4; c++)
        aq[c] = *(const s8v*)(Qp + (size_t)col * HD_ + c * 32 + quad * 8);

    const f4v fzero = {0.f, 0.f, 0.f, 0.f};
    f4v o[8];
#pragma unroll
    for (int t = 0; t < 8; t++) o[t] = fzero;
    float m = -1e30f, l = 0.f;

    const bf16* Kbase = Kb + (size_t)bh * S_ * HD_;
    const bf16* Vbase = Vt + (size_t)bh * HD_ * S_;

    // staging geometry (constant per thread across tiles):
    // K tile 64x128: granule g=p*256+tid -> row=g>>4, blk=g&15 (16B blocks)
    // V tile 128x64: row=g>>3, blk=g&7
    int kgo[4], vgo[4], klo[4], vlo[4];
#pragma unroll
    for (int p = 0; p < 4; p++) {
        const int g = p * 256 + tid;
        const int krow = g >> 4, kblk = g & 15;
        kgo[p] = krow * HD_ + kblk * 8;
        klo[p] = krow * 256 + ((kblk * 16) ^ ((krow & 7) << 4));
        const int vrow = g >> 3, vblk = g & 7;
        vgo[p] = vrow * S_ + vblk * 8;
        vlo[p] = vrow * 128 + ((vblk * 16) ^ ((vrow & 7) << 4));
    }

    // prologue: prefetch tile 0 into regs
    uint4 krg[4], vrg[4];
#pragma unroll
    for (int p = 0; p < 4; p++) {
        krg[p] = *(const uint4*)(Kbase + kgo[p]);
        vrg[p] = *(const uint4*)(Vbase + vgo[p]);
    }

    const int nkt = qb + 1;
    for (int kt = 0; kt < nkt; kt++) {
        const int k0 = kt << 6;
        __syncthreads();                       // prev-iter readers of Kl/Vl done
#pragma unroll
        for (int p = 0; p < 4; p++) {
            *(uint4*)(Kl + klo[p]) = krg[p];
            *(uint4*)(Vl + vlo[p]) = vrg[p];
        }
        __syncthreads();                       // tiles visible to all waves

        // T14: issue next tile's global loads now; consumed only at next
        // loop-top store -> latency hides under the compute below.
        if (kt + 1 < nkt) {
            const bf16* Kp2 = Kbase + (size_t)(kt + 1) * 64 * HD_;
            const bf16* Vp2 = Vbase + (kt + 1) * 64;
#pragma unroll
            for (int p = 0; p < 4; p++) {
                krg[p] = *(const uint4*)(Kp2 + kgo[p]);
                vrg[p] = *(const uint4*)(Vp2 + vgo[p]);
            }
        }

        // ---- S^T = K.Q^T : 4 sub-tiles of 16 keys ----
        f4v sc[4];
        __builtin_amdgcn_s_setprio(1);
#pragma unroll
        for (int st = 0; st < 4; st++) {
            sc[st] = fzero;
#pragma unroll
            for (int c = 0; c < 4; c++) {
                const s8v kf = *(const s8v*)(Kl + (st * 16 + col) * 256 +
                                             ((c * 64 + quad * 16) ^ sw));
                sc[st] = mfma16(kf, aq[c], sc[st]);
            }
        }
        __builtin_amdgcn_s_setprio(0);

        // ---- scores + alibi + causal mask; per-lane = one q, 16 keys ----
        float s[16];
        float mx = -1e30f;
#pragma unroll
        for (int st = 0; st < 4; st++)
#pragma unroll
            for (int r = 0; r < 4; r++) {
                const int key = k0 + st * 16 + (quad << 2) + r;
                float v = sc[st][r] * INV_NORM + slope * (float)key;
                v = (key > qg) ? -1e9f : v;
                s[st * 4 + r] = v;
                mx = fmaxf(mx, v);
            }
        mx = fmaxf(mx, __shfl_xor(mx, 16));
        mx = fmaxf(mx, __shfl_xor(mx, 32));
        const float nm = fmaxf(m, mx);
        float ps = 0.f;
#pragma unroll
        for (int i = 0; i < 16; i++) { s[i] = __expf(s[i] - nm); ps += s[i]; }
        ps += __shfl_xor(ps, 16);
        ps += __shfl_xor(ps, 32);
        const float alpha = __expf(m - nm);
        l = l * alpha + ps;
        m = nm;
#pragma unroll
        for (int t = 0; t < 8; t++) o[t] *= alpha;

        // ---- P^T (C-layout) -> B-operand layout via per-wave LDS ----
        // Pl is wave-private: no barrier needed (lgkmcnt orders write->read).
        char* plw = Pl + wave * 2048 + col * 128;
#pragma unroll
        for (int st = 0; st < 4; st++) {
            union { ushort4 u4; bf16 hh[4]; } pk;
#pragma unroll
            for (int r = 0; r < 4; r++) pk.hh[r] = __float2bfloat16(s[st * 4 + r]);
            *(ushort4*)(plw + ((st * 32 + quad * 8) ^ sw)) = pk.u4;
        }
        const s8v pf0 = *(const s8v*)(plw + ((quad * 16) ^ sw));
        const s8v pf1 = *(const s8v*)(plw + ((64 + quad * 16) ^ sw));

        // ---- ctx^T += V^T . P^T ----
        __builtin_amdgcn_s_setprio(1);
#pragma unroll
        for (int t = 0; t < 8; t++) {
            const s8v vf0 = *(const s8v*)(Vl + (t * 16 + col) * 128 +
                                          ((quad * 16) ^ sw));
            o[t] = mfma16(vf0, pf0, o[t]);
            const s8v vf1 = *(const s8v*)(Vl + (t * 16 + col) * 128 +
                                          ((64 + quad * 16) ^ sw));
            o[t] = mfma16(vf1, pf1, o[t]);
        }
        __builtin_amdgcn_s_setprio(0);
    }

    // ---- epilogue: o[t][r] = ctx^T[d=t*16+quad*4+r][q] ----
    const float rl = 1.0f / l;
#pragma unroll
    for (int t = 0; t < 8; t++) {
        union { ushort4 u4; bf16 hh[4]; } pk;
#pragma unroll
        for (int r = 0; r < 4; r++) pk.hh[r] = __float2bfloat16(o[t][r] * rl);
        *(ushort4*)&ctx[((size_t)(b * S_) + qg) * D_ + h * HD_ + t * 16 + (quad << 2)] =
            pk.u4;
    }
}

extern "C" void kernel_launch(void* const* d_in, const int* in_sizes, int n_in,
                              void* d_out, int out_size, void* d_ws, size_t ws_size,
                              hipStream_t stream)
{
    const float* hs    = (const float*)d_in[0];
    const float* resid = (const float*)d_in[1];
    // d_in[2] = alibi: analytic (slope = 2^(-0.5*(h+1)), score += slope*key)
    // d_in[3] = attention_mask: pure causal tril/-1e9, applied analytically
    const float* Wqkv  = (const float*)d_in[4];
    const float* bqkv  = (const float*)d_in[5];
    const float* Wd    = (const float*)d_in[6];
    const float* bd    = (const float*)d_in[7];
    float* out = (float*)d_out;

    const size_t seg  = (size_t)B_ * H_ * S_ * HD_;   // 8,388,608 elems
    const size_t nHS  = (size_t)B_ * S_ * D_;         // 8,388,608
    const size_t nWq  = (size_t)3 * D_ * D_;          // 12,582,912
    const size_t nWd  = (size_t)D_ * D_;              // 4,194,304
    bf16* Qbuf = (bf16*)d_ws;
    bf16* Kbuf = Qbuf + seg;
    bf16* Vtb  = Kbuf + seg;
    bf16* ctx  = Vtb + seg;
    bf16* hsb  = ctx + seg;
    bf16* Wqb  = hsb + nHS;
    bf16* Wdb  = Wqb + nWq;          // end: 58,720,256 bf16 = 117.4 MB

    cvt_f32_bf16<<<(int)(nHS / 4 + 255) / 256, 256, 0, stream>>>(hs, hsb, (int)(nHS / 4));
    cvt_f32_bf16<<<(int)(nWq / 4 + 255) / 256, 256, 0, stream>>>(Wqkv, Wqb, (int)(nWq / 4));
    cvt_f32_bf16<<<(int)(nWd / 4 + 255) / 256, 256, 0, stream>>>(Wd, Wdb, (int)(nWd / 4));

    gemm_bt<0><<<dim3(48, 32), 256, 0, stream>>>(hsb, Wqb, bqkv, nullptr,
                                                 Qbuf, Kbuf, Vtb, nullptr, 2048);
    attn<<<dim3(32, 32), 256, 0, stream>>>(Qbuf, Kbuf, Vtb, ctx);
    gemm_bt<1><<<dim3(16, 32), 256, 0, stream>>>(ctx, Wdb, bd, resid,
                                                 nullptr, nullptr, nullptr, out, 2048);
}

// Round 2
// 472.013 us; speedup vs baseline: 1.3129x; 1.1713x over previous
//
#include <hip/hip_runtime.h>
#include <hip/hip_bf16.h>

typedef __hip_bfloat16 bf16;
typedef __attribute__((ext_vector_type(8))) short s8v;   // 8 bf16 = 4 VGPRs (MFMA A/B frag)
typedef __attribute__((ext_vector_type(4))) float f4v;   // MFMA C/D frag

#define B_  2
#define S_  2048
#define D_  2048
#define H_  16
#define HD_ 128
#define INV_NORM 0.08838834764831845f

static __device__ __forceinline__ f4v mfma16(s8v a, s8v b, f4v c) {
    return __builtin_amdgcn_mfma_f32_16x16x32_bf16(a, b, c, 0, 0, 0);
}

static __device__ __forceinline__ void gload_lds(const void* gp, void* lp) {
    __builtin_amdgcn_global_load_lds(
        (const __attribute__((address_space(1))) unsigned int*)gp,
        (__attribute__((address_space(3))) unsigned int*)lp, 16, 0, 0);
}

// fp32 -> bf16 elementwise convert, 4 elems/thread
__global__ __launch_bounds__(256)
void cvt_f32_bf16(const float* __restrict__ src, bf16* __restrict__ dst, int n4)
{
    int i = blockIdx.x * 256 + threadIdx.x;
    if (i < n4) {
        float4 f = ((const float4*)src)[i];
        union { ushort4 u4; bf16 h[4]; } p;
        p.h[0] = __float2bfloat16(f.x);
        p.h[1] = __float2bfloat16(f.y);
        p.h[2] = __float2bfloat16(f.z);
        p.h[3] = __float2bfloat16(f.w);
        ((ushort4*)dst)[i] = p.u4;
    }
}

// C[M,N] = A[M,K] @ B[N,K]^T + bias; MODE 0: scatter to Q/K/V^T (bf16);
// MODE 1: + residual -> fp32 out. Block: 256 thr (4 waves), tile 128x128, BK=32.
// m97 structure: global_load_lds width-16 staging, unpadded [128][32] LDS.
template <int MODE>
__global__ __launch_bounds__(256)
void gemm_bt(const bf16* __restrict__ A, const bf16* __restrict__ Bw,
             const float* __restrict__ bias, const float* __restrict__ resid,
             bf16* __restrict__ o0, bf16* __restrict__ o1, bf16* __restrict__ o2,
             float* __restrict__ of, int K)
{
    __shared__ __align__(16) bf16 Al[128][32];   // unpadded: lane-contiguous for lds-DMA
    __shared__ __align__(16) bf16 Bl[128][32];
    const int tid  = threadIdx.x;
    const int wave = tid >> 6, lane = tid & 63;
    const int col  = lane & 15, quad = lane >> 4;
    const int wm = (wave >> 1) << 6, wn = (wave & 1) << 6;
    const int bn = blockIdx.x, bm = blockIdx.y;
    const bf16* Ab = A  + (size_t)bm * 128 * K;
    const bf16* Bb = Bw + (size_t)bn * 128 * K;

    const f4v fzero = {0.f, 0.f, 0.f, 0.f};
    f4v acc[4][4];
#pragma unroll
    for (int i = 0; i < 4; i++)
#pragma unroll
        for (int j = 0; j < 4; j++) acc[i][j] = fzero;

    for (int k0 = 0; k0 < K; k0 += 32) {
        // stage A,B tiles: granule g covers row=g>>2, ko=(g&3)*8 ; LDS dest = base + g*16
#pragma unroll
        for (int p = 0; p < 2; p++) {
            const int g = p * 256 + tid;
            const int r = g >> 2, ko = (g & 3) << 3;
            gload_lds(Ab + (size_t)r * K + k0 + ko, (char*)&Al[0][0] + (size_t)g * 16);
            gload_lds(Bb + (size_t)r * K + k0 + ko, (char*)&Bl[0][0] + (size_t)g * 16);
        }
        __syncthreads();
        s8v af[4], bfr[4];
#pragma unroll
        for (int i = 0; i < 4; i++) af[i]  = *(const s8v*)&Al[wm + i * 16 + col][quad * 8];
#pragma unroll
        for (int j = 0; j < 4; j++) bfr[j] = *(const s8v*)&Bl[wn + j * 16 + col][quad * 8];
#pragma unroll
        for (int i = 0; i < 4; i++)
#pragma unroll
            for (int j = 0; j < 4; j++)
                acc[i][j] = mfma16(af[i], bfr[j], acc[i][j]);
        __syncthreads();
    }

    // Epilogue. C/D layout: row = quad*4+reg, col = lane&15 (HW-verified m89/m91).
    if (MODE == 0) {
        // 128-col block == exactly one (h,t): 6144 = 16h * 3t * 128hd
        const int t = bn % 3, h = bn / 3;
#pragma unroll
        for (int j = 0; j < 4; j++) {
            const int c = wn + j * 16 + col;                      // hd in [0,128)
            const float bv = bias[bn * 128 + c];
#pragma unroll
            for (int i = 0; i < 4; i++) {
                const int r  = (bm << 7) + wm + i * 16 + (quad << 2); // 4 consecutive rows
                const int bb = r >> 11, s = r & (S_ - 1);
                if (t == 2) {
                    // V^T[b,h, hd, s]: 4 consecutive s -> one 8B store
                    union { ushort4 u4; bf16 hh[4]; } pk;
#pragma unroll
                    for (int rg = 0; rg < 4; rg++)
                        pk.hh[rg] = __float2bfloat16(acc[i][j][rg] + bv);
                    *(ushort4*)(o2 + ((size_t)(bb * H_ + h) * HD_ + c) * S_ + s) = pk.u4;
                } else {
                    bf16* dst = (t == 0) ? o0 : o1;   // Q or K: [b,h,s,hd]
#pragma unroll
                    for (int rg = 0; rg < 4; rg++)
                        dst[((size_t)(bb * H_ + h) * S_ + (s + rg)) * HD_ + c] =
                            __float2bfloat16(acc[i][j][rg] + bv);
                }
            }
        }
    } else {
#pragma unroll
        for (int j = 0; j < 4; j++) {
            const int c = (bn << 7) + wn + j * 16 + col;
            const float bv = bias[c];
#pragma unroll
            for (int i = 0; i < 4; i++) {
                const int r = (bm << 7) + wm + i * 16 + (quad << 2);
#pragma unroll
                for (int rg = 0; rg < 4; rg++) {
                    const size_t idx = (size_t)(r + rg) * D_ + c;
                    of[idx] = acc[i][j][rg] + bv + resid[idx];
                }
            }
        }
    }
}

// Flash attention, transposed-score formulation.
// Block: 256 thr (4 waves), 64 q-rows (wave w -> rows q0+w*16). K-tiles of 64 keys
// staged in LDS, shared by all waves. S^T = K.Q^T (C: row=key, col=q) -> softmax
// reduction is 15 in-lane ops + 2 shfls. O accumulated as ctx^T = V^T.P^T.
// Q,K: [B,H,S,HD] bf16; V^T: [B,H,HD,S] bf16; ctx out bf16 [B,S,H*HD].
//
// R2 changes vs R1 (R1 post-mortem: 485 MB WRITE_SIZE = krg/vrg reg-prefetch
// spilling every iter under the 128-VGPR cap of launch_bounds(256,4)):
//  - prefetch moved to global_load_lds (ZERO VGPR cost) into DOUBLE-BUFFERED
//    K/V LDS tiles. Swizzle preserved per rule 21: linear LDS dest +
//    inverse-swizzled global SOURCE (involution blk^=row&7 on 16B blocks);
//    physical LDS contents identical to the R1-verified layout, read side
//    unchanged.
//  - LDS 72 KB -> 2 blocks/CU; launch_bounds(256,2) -> 256-VGPR cap, no
//    spill possible (live set ~110).
//  - ONE barrier per iteration: issue tile kt+1 DMA at loop top, compute on
//    tile kt, barrier (compiler's vmcnt(0) drain) flips buffers. HBM latency
//    hides under the full MFMA+softmax phase.
//  - qb balance swizzle, setprio, analytic alibi/mask: kept from R1.
__global__ __launch_bounds__(256, 2)
void attn(const bf16* __restrict__ Qb, const bf16* __restrict__ Kb,
          const bf16* __restrict__ Vt, bf16* __restrict__ ctx)
{
    __shared__ __align__(16) char Ksm[2][64 * 256];     // [key][hd=128], swizzled
    __shared__ __align__(16) char Vsm[2][128 * 128];    // [hd][key=64], swizzled
    __shared__ __align__(16) char Pl[4 * 16 * 128];     // per-wave [q=16][key=64]

    const int x = blockIdx.x;
    const int bh = blockIdx.y;                             // 0..31
    const int u = (bh >> 3) & 1;
    const int qb = u ? x : (int)gridDim.x - 1 - x;         // per-CU balance: {31-x, x}
    const int b = bh >> 4, h = bh & 15;
    const int tid = threadIdx.x;
    const int wave = tid >> 6, lane = tid & 63;
    const int col = lane & 15, quad = lane >> 4;
    const int q0 = qb << 6;
    const int qg = q0 + wave * 16 + col;          // this lane's q row (global)
    const float slope = exp2f(-0.5f * (float)(h + 1));
    const int sw = (col & 7) << 4;                // fragment-read swizzle term

    // Q fragments (B-operand): n=q=col, k=quad*8+j (+32c)
    const bf16* Qp = Qb + ((size_t)bh * S_ + q0 + wave * 16) * HD_;
    s8v aq[4];
#pragma unroll
    for (int c = 0; c < 4; c++)
        aq[c] = *(const s8v*)(Qp + (size_t)col * HD_ + c * 32 + quad * 8);

    const f4v fzero = {0.f, 0.f, 0.f, 0.f};
    f4v o[8];
#pragma unroll
    for (int t = 0; t < 8; t++) o[t] = fzero;
    float m = -1e30f, l = 0.f;

    const bf16* Kbase = Kb + (size_t)bh * S_ * HD_;
    const bf16* Vbase = Vt + (size_t)bh * HD_ * S_;

    // DMA staging geometry. Granule g = p*256+tid -> linear LDS byte g*16
    // (per-wave lane-consecutive, as global_load_lds requires). Global source
    // is PRE-swizzled so that swizzled reads see the data: 16B-block index
    // XOR'd with (row&7) — an involution, same physical layout as R1.
    int ksrc[4], vsrc[4];
#pragma unroll
    for (int p = 0; p < 4; p++) {
        const int g = p * 256 + tid;
        const int kr = g >> 4, kb = g & 15;       // K: 16 granules/row of 128 bf16
        ksrc[p] = kr * HD_ + ((kb ^ (kr & 7)) << 3);
        const int vr = g >> 3, vb = g & 7;        // V: 8 granules/row of 64 bf16
        vsrc[p] = vr * S_ + ((vb ^ (vr & 7)) << 3);
    }
    const int ldst = tid << 4;                    // + p*4096 per granule

    // prologue: DMA tile 0 into buffer 0
    {
        const bf16* Kp = Kbase;
        const bf16* Vp = Vbase;
#pragma unroll
        for (int p = 0; p < 4; p++) {
            gload_lds(Kp + ksrc[p], Ksm[0] + p * 4096 + ldst);
            gload_lds(Vp + vsrc[p], Vsm[0] + p * 4096 + ldst);
        }
    }
    __syncthreads();   // vmcnt(0) drain: tile 0 resident

    const int nkt = qb + 1;
    for (int kt = 0; kt < nkt; kt++) {
        const int cur = kt & 1;
        const int k0 = kt << 6;

        // issue next tile's DMA now; drained only at this iter's end barrier,
        // so HBM latency hides under the whole compute phase below.
        if (kt + 1 < nkt) {
            const bf16* Kp = Kbase + (size_t)(kt + 1) * 64 * HD_;
            const bf16* Vp = Vbase + (kt + 1) * 64;
            char* Kd = Ksm[cur ^ 1];
            char* Vd = Vsm[cur ^ 1];
#pragma unroll
            for (int p = 0; p < 4; p++) {
                gload_lds(Kp + ksrc[p], Kd + p * 4096 + ldst);
                gload_lds(Vp + vsrc[p], Vd + p * 4096 + ldst);
            }
        }
        const char* Kcur = Ksm[cur];
        const char* Vcur = Vsm[cur];

        // ---- S^T = K.Q^T : 4 sub-tiles of 16 keys ----
        f4v sc[4];
        __builtin_amdgcn_s_setprio(1);
#pragma unroll
        for (int st = 0; st < 4; st++) {
            sc[st] = fzero;
#pragma unroll
            for (int c = 0; c < 4; c++) {
                const s8v kf = *(const s8v*)(Kcur + (st * 16 + col) * 256 +
                                             ((c * 64 + quad * 16) ^ sw));
                sc[st] = mfma16(kf, aq[c], sc[st]);
            }
        }
        __builtin_amdgcn_s_setprio(0);

        // ---- scores + alibi + causal mask; per-lane = one q, 16 keys ----
        float s[16];
        float mx = -1e30f;
#pragma unroll
        for (int st = 0; st < 4; st++)
#pragma unroll
            for (int r = 0; r < 4; r++) {
                const int key = k0 + st * 16 + (quad << 2) + r;
                float v = sc[st][r] * INV_NORM + slope * (float)key;
                v = (key > qg) ? -1e9f : v;
                s[st * 4 + r] = v;
                mx = fmaxf(mx, v);
            }
        mx = fmaxf(mx, __shfl_xor(mx, 16));
        mx = fmaxf(mx, __shfl_xor(mx, 32));
        const float nm = fmaxf(m, mx);
        float ps = 0.f;
#pragma unroll
        for (int i = 0; i < 16; i++) { s[i] = __expf(s[i] - nm); ps += s[i]; }
        ps += __shfl_xor(ps, 16);
        ps += __shfl_xor(ps, 32);
        const float alpha = __expf(m - nm);
        l = l * alpha + ps;
        m = nm;
#pragma unroll
        for (int t = 0; t < 8; t++) o[t] *= alpha;

        // ---- P^T (C-layout) -> B-operand layout via per-wave LDS ----
        // Pl is wave-private: lgkmcnt orders write->read, no barrier needed.
        char* plw = Pl + wave * 2048 + col * 128;
#pragma unroll
        for (int st = 0; st < 4; st++) {
            union { ushort4 u4; bf16 hh[4]; } pk;
#pragma unroll
            for (int r = 0; r < 4; r++) pk.hh[r] = __float2bfloat16(s[st * 4 + r]);
            *(ushort4*)(plw + ((st * 32 + quad * 8) ^ sw)) = pk.u4;
        }
        const s8v pf0 = *(const s8v*)(plw + ((quad * 16) ^ sw));
        const s8v pf1 = *(const s8v*)(plw + ((64 + quad * 16) ^ sw));

        // ---- ctx^T += V^T . P^T ----
        __builtin_amdgcn_s_setprio(1);
#pragma unroll
        for (int t = 0; t < 8; t++) {
            const s8v vf0 = *(const s8v*)(Vcur + (t * 16 + col) * 128 +
                                          ((quad * 16) ^ sw));
            o[t] = mfma16(vf0, pf0, o[t]);
            const s8v vf1 = *(const s8v*)(Vcur + (t * 16 + col) * 128 +
                                          ((64 + quad * 16) ^ sw));
            o[t] = mfma16(vf1, pf1, o[t]);
        }
        __builtin_amdgcn_s_setprio(0);

        __syncthreads();   // drain next-tile DMA + protect buffers; flip
    }

    // ---- epilogue: o[t][r] = ctx^T[d=t*16+quad*4+r][q] ----
    const float rl = 1.0f / l;
#pragma unroll
    for (int t = 0; t < 8; t++) {
        union { ushort4 u4; bf16 hh[4]; } pk;
#pragma unroll
        for (int r = 0; r < 4; r++) pk.hh[r] = __float2bfloat16(o[t][r] * rl);
        *(ushort4*)&ctx[((size_t)(b * S_) + qg) * D_ + h * HD_ + t * 16 + (quad << 2)] =
            pk.u4;
    }
}

extern "C" void kernel_launch(void* const* d_in, const int* in_sizes, int n_in,
                              void* d_out, int out_size, void* d_ws, size_t ws_size,
                              hipStream_t stream)
{
    const float* hs    = (const float*)d_in[0];
    const float* resid = (const float*)d_in[1];
    // d_in[2] = alibi: analytic (slope = 2^(-0.5*(h+1)), score += slope*key)
    // d_in[3] = attention_mask: pure causal tril/-1e9, applied analytically
    const float* Wqkv  = (const float*)d_in[4];
    const float* bqkv  = (const float*)d_in[5];
    const float* Wd    = (const float*)d_in[6];
    const float* bd    = (const float*)d_in[7];
    float* out = (float*)d_out;

    const size_t seg  = (size_t)B_ * H_ * S_ * HD_;   // 8,388,608 elems
    const size_t nHS  = (size_t)B_ * S_ * D_;         // 8,388,608
    const size_t nWq  = (size_t)3 * D_ * D_;          // 12,582,912
    const size_t nWd  = (size_t)D_ * D_;              // 4,194,304
    bf16* Qbuf = (bf16*)d_ws;
    bf16* Kbuf = Qbuf + seg;
    bf16* Vtb  = Kbuf + seg;
    bf16* ctx  = Vtb + seg;
    bf16* hsb  = ctx + seg;
    bf16* Wqb  = hsb + nHS;
    bf16* Wdb  = Wqb + nWq;          // end: 58,720,256 bf16 = 117.4 MB

    cvt_f32_bf16<<<(int)(nHS / 4 + 255) / 256, 256, 0, stream>>>(hs, hsb, (int)(nHS / 4));
    cvt_f32_bf16<<<(int)(nWq / 4 + 255) / 256, 256, 0, stream>>>(Wqkv, Wqb, (int)(nWq / 4));
    cvt_f32_bf16<<<(int)(nWd / 4 + 255) / 256, 256, 0, stream>>>(Wd, Wdb, (int)(nWd / 4));

    gemm_bt<0><<<dim3(48, 32), 256, 0, stream>>>(hsb, Wqb, bqkv, nullptr,
                                                 Qbuf, Kbuf, Vtb, nullptr, 2048);
    attn<<<dim3(32, 32), 256, 0, stream>>>(Qbuf, Kbuf, Vtb, ctx);
    gemm_bt<1><<<dim3(16, 32), 256, 0, stream>>>(ctx, Wdb, bd, resid,
                                                 nullptr, nullptr, nullptr, out, 2048);
}

// Round 5
// 450.742 us; speedup vs baseline: 1.3749x; 1.0472x over previous
//
#include <hip/hip_runtime.h>
#include <hip/hip_bf16.h>

typedef __hip_bfloat16 bf16;
typedef __attribute__((ext_vector_type(8))) short s8v;   // 8 bf16 = 4 VGPRs (MFMA A/B frag)
typedef __attribute__((ext_vector_type(4))) float f4v;   // MFMA C/D frag

#define B_  2
#define S_  2048
#define D_  2048
#define H_  16
#define HD_ 128
#define INV_NORM 0.08838834764831845f

static __device__ __forceinline__ f4v mfma16(s8v a, s8v b, f4v c) {
    return __builtin_amdgcn_mfma_f32_16x16x32_bf16(a, b, c, 0, 0, 0);
}

static __device__ __forceinline__ void gload_lds(const void* gp, void* lp) {
    __builtin_amdgcn_global_load_lds(
        (const __attribute__((address_space(1))) unsigned int*)gp,
        (__attribute__((address_space(3))) unsigned int*)lp, 16, 0, 0);
}

// fp32 -> bf16 elementwise convert, 4 elems/thread
__global__ __launch_bounds__(256)
void cvt_f32_bf16(const float* __restrict__ src, bf16* __restrict__ dst, int n4)
{
    int i = blockIdx.x * 256 + threadIdx.x;
    if (i < n4) {
        float4 f = ((const float4*)src)[i];
        union { ushort4 u4; bf16 h[4]; } p;
        p.h[0] = __float2bfloat16(f.x);
        p.h[1] = __float2bfloat16(f.y);
        p.h[2] = __float2bfloat16(f.z);
        p.h[3] = __float2bfloat16(f.w);
        ((ushort4*)dst)[i] = p.u4;
    }
}

// Old m97-structure 128x128 GEMM — retained for MODE 1 (dense out, N=2048:
// a 256^2 grid would be only 128 blocks = half the CUs idle).
template <int MODE>
__global__ __launch_bounds__(256)
void gemm_bt(const bf16* __restrict__ A, const bf16* __restrict__ Bw,
             const float* __restrict__ bias, const float* __restrict__ resid,
             bf16* __restrict__ o0, bf16* __restrict__ o1, bf16* __restrict__ o2,
             float* __restrict__ of, int K)
{
    __shared__ __align__(16) bf16 Al[128][32];
    __shared__ __align__(16) bf16 Bl[128][32];
    const int tid  = threadIdx.x;
    const int wave = tid >> 6, lane = tid & 63;
    const int col  = lane & 15, quad = lane >> 4;
    const int wm = (wave >> 1) << 6, wn = (wave & 1) << 6;
    const int bn = blockIdx.x, bm = blockIdx.y;
    const bf16* Ab = A  + (size_t)bm * 128 * K;
    const bf16* Bb = Bw + (size_t)bn * 128 * K;

    const f4v fzero = {0.f, 0.f, 0.f, 0.f};
    f4v acc[4][4];
#pragma unroll
    for (int i = 0; i < 4; i++)
#pragma unroll
        for (int j = 0; j < 4; j++) acc[i][j] = fzero;

    for (int k0 = 0; k0 < K; k0 += 32) {
#pragma unroll
        for (int p = 0; p < 2; p++) {
            const int g = p * 256 + tid;
            const int r = g >> 2, ko = (g & 3) << 3;
            gload_lds(Ab + (size_t)r * K + k0 + ko, (char*)&Al[0][0] + (size_t)g * 16);
            gload_lds(Bb + (size_t)r * K + k0 + ko, (char*)&Bl[0][0] + (size_t)g * 16);
        }
        __syncthreads();
        s8v af[4], bfr[4];
#pragma unroll
        for (int i = 0; i < 4; i++) af[i]  = *(const s8v*)&Al[wm + i * 16 + col][quad * 8];
#pragma unroll
        for (int j = 0; j < 4; j++) bfr[j] = *(const s8v*)&Bl[wn + j * 16 + col][quad * 8];
#pragma unroll
        for (int i = 0; i < 4; i++)
#pragma unroll
            for (int j = 0; j < 4; j++)
                acc[i][j] = mfma16(af[i], bfr[j], acc[i][j]);
        __syncthreads();
    }

    if (MODE == 0) {
        const int t = bn % 3, h = bn / 3;
#pragma unroll
        for (int j = 0; j < 4; j++) {
            const int c = wn + j * 16 + col;
            const float bv = bias[bn * 128 + c];
#pragma unroll
            for (int i = 0; i < 4; i++) {
                const int r  = (bm << 7) + wm + i * 16 + (quad << 2);
                const int bb = r >> 11, s = r & (S_ - 1);
                if (t == 2) {
                    union { ushort4 u4; bf16 hh[4]; } pk;
#pragma unroll
                    for (int rg = 0; rg < 4; rg++)
                        pk.hh[rg] = __float2bfloat16(acc[i][j][rg] + bv);
                    *(ushort4*)(o2 + ((size_t)(bb * H_ + h) * HD_ + c) * S_ + s) = pk.u4;
                } else {
                    bf16* dst = (t == 0) ? o0 : o1;
#pragma unroll
                    for (int rg = 0; rg < 4; rg++)
                        dst[((size_t)(bb * H_ + h) * S_ + (s + rg)) * HD_ + c] =
                            __float2bfloat16(acc[i][j][rg] + bv);
                }
            }
        }
    } else {
#pragma unroll
        for (int j = 0; j < 4; j++) {
            const int c = (bn << 7) + wn + j * 16 + col;
            const float bv = bias[c];
#pragma unroll
            for (int i = 0; i < 4; i++) {
                const int r = (bm << 7) + wm + i * 16 + (quad << 2);
#pragma unroll
                for (int rg = 0; rg < 4; rg++) {
                    const size_t idx = (size_t)(r + rg) * D_ + c;
                    of[idx] = acc[i][j][rg] + bv + resid[idx];
                }
            }
        }
    }
}

// ---------------------------------------------------------------------------
// R5 == R4 resubmission (R3/R4 bench errors carried no timing fields ->
// container-level infra failure, not a kernel result; kernel re-audited:
// ledger + cross-wave barrier composition + exact-fit bounds all verified.
// Pre-committed: if this fails a third time, next round reverts to the
// R2-verified kernel to split infra from kernel).
//
// 8-phase 256x256 QKV GEMM (T3+T4 counted-vmcnt schedule, plain HIP).
// M=4096, N=6144, K=2048 fixed. 512 thr (8 waves, 2M x 4N interleaved),
// BK=64, LDS = 2 x (A 32K + B 32K) = 128 KB exactly (1 block/CU; 128 KiB
// static LDS precedented on MI355X by learn_hip m201's template kernel).
//
// Wave tiling (INTERLEAVED so phase fragments align with 16KB chunks):
//   wave (wr=wid>>2, wc=wid&3); M-frag mi -> tile row mi*32 + wr*16;
//   N-frag nj -> tile col nj*64 + wc*16. mi 0-3 reads chunk A-lo, mi 4-7
//   A-hi; nj 0-1 B-lo, nj 2-3 B-hi.
// Phase q computes one C-quadrant (16 MFMA): q0 needs A-lo+B-lo, q1 A-hi,
//   q2 B-hi, q3 register-only.
// vmcnt ledger (per wave; 2 loads per chunk, issue order A-lo,B-lo,A-hi,B-hi):
//   iter entry: 8 outstanding. ph0 issues 2 -> 10, vmcnt(6) drains
//   A-lo+B-lo (exactly what ph0 reads). ph1 issues 2 -> 8, vmcnt(6) drains
//   A-hi. ph2 issues 2 -> 8, vmcnt(6) drains B-hi. ph3 issues 2 -> 8 =
//   invariant. Tail tile: vmcnt(4)/(2)/(0). Never vmcnt(0) in the main
//   loop (T4). Cross-wave safety: each wave's vmcnt retires ITS OWN chunk
//   loads pre-barrier; the barrier universally quantifies that over all 8
//   waves (same composition as m201's stage->barrier->lgkmcnt pattern).
// RACE FIX (kept from R4): post-MM(q2) barrier — a wave reaching it has
//   issued its q2 MFMAs, which required lgkmcnt-drain of its RD_B reads of
//   bufB; so all reads of bufB complete before any wave can issue next-iter
//   ph0 DMA into that buffer. 4 barriers/tile.
// T2 swizzle via pre-swizzled DMA source (involution blk^=(row&7) on 16B
//   blocks; row&7==col&7 for all fragment reads -> 2 const addr terms).
// A/B frags carried across phases: LDS read = 24 KB/wave/tile (minimum).
// ---------------------------------------------------------------------------
#define VMW(s) asm volatile("s_waitcnt " s ::: "memory")
#define BARR() { __builtin_amdgcn_s_barrier(); asm volatile("" ::: "memory"); }

#define RD_A(dst, mibase)                                                       \
  _Pragma("unroll") for (int mi = 0; mi < 4; ++mi) {                            \
    dst[mi][0] = *(const s8v*)(lds + bufB + aR + (mibase + mi) * 4096 + sx0);   \
    dst[mi][1] = *(const s8v*)(lds + bufB + aR + (mibase + mi) * 4096 + sx1);   \
  }
#define RD_B(njbase)                                                            \
  _Pragma("unroll") for (int nj = 0; nj < 2; ++nj) {                            \
    bfr[nj][0] = *(const s8v*)(lds + bufB + bRo + (njbase + nj) * 8192 + sx0);  \
    bfr[nj][1] = *(const s8v*)(lds + bufB + bRo + (njbase + nj) * 8192 + sx1);  \
  }
#define MM(af, mibase, njbase)                                                  \
  __builtin_amdgcn_s_setprio(1);                                                \
  _Pragma("unroll") for (int mi = 0; mi < 4; ++mi)                              \
  _Pragma("unroll") for (int nj = 0; nj < 2; ++nj) {                            \
    acc[mibase + mi][njbase + nj] =                                             \
        mfma16(af[mi][0], bfr[nj][0], acc[mibase + mi][njbase + nj]);           \
    acc[mibase + mi][njbase + nj] =                                             \
        mfma16(af[mi][1], bfr[nj][1], acc[mibase + mi][njbase + nj]);           \
  }                                                                             \
  __builtin_amdgcn_s_setprio(0);

#define KTILE(DOPRE, VA, VB, VC)                                                \
  {                                                                             \
    const int bufB = cur << 16, bufN = (cur ^ 1) << 16;                         \
    const size_t t1 = (size_t)(kt + 1) * 64;                                    \
    /* phase 0: issue A-lo', wait A-lo+B-lo, compute q0 */                      \
    if (DOPRE) { gload_lds(gA + t1 + srcO0, lds + bufN + 0 + dst0);             \
                 gload_lds(gA + t1 + srcO1, lds + bufN + 0 + dst1); }           \
    VMW(VA); BARR();                                                            \
    RD_A(a0, 0); RD_B(0);                                                       \
    MM(a0, 0, 0);                                                               \
    /* phase 1: issue B-lo', wait A-hi, compute q1 */                           \
    if (DOPRE) { gload_lds(gB + t1 + srcO0, lds + bufN + 32768 + dst0);         \
                 gload_lds(gB + t1 + srcO1, lds + bufN + 32768 + dst1); }       \
    VMW(VB); BARR();                                                            \
    RD_A(a1, 4);                                                                \
    MM(a1, 4, 0);                                                               \
    /* phase 2: issue A-hi', wait B-hi, compute q2 */                           \
    if (DOPRE) { gload_lds(gA2 + t1 + srcO0, lds + bufN + 16384 + dst0);        \
                 gload_lds(gA2 + t1 + srcO1, lds + bufN + 16384 + dst1); }      \
    VMW(VC); BARR();                                                            \
    RD_B(2);                                                                    \
    MM(a0, 0, 2);                                                               \
    BARR(); /* RACE FIX: bufB reads complete before next-iter DMA into it */    \
    /* phase 3: issue B-hi', compute q3 (registers only) */                     \
    if (DOPRE) { gload_lds(gB2 + t1 + srcO0, lds + bufN + 49152 + dst0);        \
                 gload_lds(gB2 + t1 + srcO1, lds + bufN + 49152 + dst1); }      \
    MM(a1, 4, 2);                                                               \
  }

__global__ __launch_bounds__(512, 2)
void gemm_qkv8(const bf16* __restrict__ A, const bf16* __restrict__ Bw,
               const float* __restrict__ bias,
               bf16* __restrict__ o0, bf16* __restrict__ o1, bf16* __restrict__ o2)
{
    __shared__ __align__(16) char lds[131072];
    const int tid  = threadIdx.x;
    const int wave = tid >> 6, lane = tid & 63;
    const int col  = lane & 15, quad = lane >> 4;
    const int wr   = wave >> 2, wc = wave & 3;

    // XCD-chunked bijective block swizzle (nwg=384, 384%8==0 -> simple form):
    int id = (int)blockIdx.y * 24 + (int)blockIdx.x;
    id = (id & 7) * 48 + (id >> 3);
    const int bm = id / 24, bn = id % 24;

    const bf16* gA  = A  + (size_t)bm * 256 * 2048;
    const bf16* gA2 = gA + (size_t)128 * 2048;
    const bf16* gB  = Bw + (size_t)bn * 256 * 2048;
    const bf16* gB2 = gB + (size_t)128 * 2048;

    // DMA staging geometry: granule g -> LDS byte chunk+g*16 (linear,
    // lane-consecutive); source k-blk pre-swizzled (blk ^ (row&7)).
    const int r0   = tid >> 3, bk0 = tid & 7;
    const int srcO0 = r0 * 2048 + ((bk0 ^ (r0 & 7)) << 3);
    const int srcO1 = srcO0 + 64 * 2048;            // rows +64, same (row&7)
    const int dst0 = tid * 16, dst1 = dst0 + 8192;

    // fragment-read addressing: row&7 == col&7 for every frag row
    const int sx0 = ((quad ^ (col & 7)) << 4);          // ks=0 swizzled k-blk
    const int sx1 = (((4 + quad) ^ (col & 7)) << 4);    // ks=1
    const int aR  = (wr * 16 + col) * 128;              // + mi*4096
    const int bRo = (wc * 16 + col) * 128 + 32768;      // + nj*8192

    const f4v fzero = {0.f, 0.f, 0.f, 0.f};
    f4v acc[8][4];
#pragma unroll
    for (int i = 0; i < 8; i++)
#pragma unroll
        for (int j = 0; j < 4; j++) acc[i][j] = fzero;
    s8v a0[4][2], a1[4][2], bfr[2][2];

    // prologue: stage tile 0 into buffer 0, chunk order {A-lo,B-lo,A-hi,B-hi}
    gload_lds(gA  + srcO0, lds + 0     + dst0);
    gload_lds(gA  + srcO1, lds + 0     + dst1);
    gload_lds(gB  + srcO0, lds + 32768 + dst0);
    gload_lds(gB  + srcO1, lds + 32768 + dst1);
    gload_lds(gA2 + srcO0, lds + 16384 + dst0);
    gload_lds(gA2 + srcO1, lds + 16384 + dst1);
    gload_lds(gB2 + srcO0, lds + 49152 + dst0);
    gload_lds(gB2 + srcO1, lds + 49152 + dst1);

    int cur = 0;
    for (int kt = 0; kt < 31; ++kt) {
        KTILE(1, "vmcnt(6)", "vmcnt(6)", "vmcnt(6)");
        cur ^= 1;
    }
    {   // tail tile: nothing in flight behind it -> descending waits
        const int kt = 31;
        KTILE(0, "vmcnt(4)", "vmcnt(2)", "vmcnt(0)");
    }

    // epilogue: scatter to Q / K / V^T. col-group = nj>>1 (wc*16+col < 64).
#pragma unroll
    for (int mi = 0; mi < 8; ++mi) {
#pragma unroll
        for (int nj = 0; nj < 4; ++nj) {
            const int cg = bn * 2 + (nj >> 1);          // 128-col group id
            const int t3 = cg % 3, hh = cg / 3;
            const int hd = (nj & 1) * 64 + wc * 16 + col;
            const float bv = bias[cg * 128 + hd];
            const int r = bm * 256 + mi * 32 + wr * 16 + (quad << 2);
            const int bi = r >> 11, srow = r & (S_ - 1);
            if (t3 == 2) {
                union { ushort4 u4; bf16 hv[4]; } pk;
#pragma unroll
                for (int rg = 0; rg < 4; ++rg)
                    pk.hv[rg] = __float2bfloat16(acc[mi][nj][rg] + bv);
                *(ushort4*)(o2 + ((size_t)(bi * H_ + hh) * HD_ + hd) * S_ + srow) = pk.u4;
            } else {
                bf16* dst = (t3 == 0) ? o0 : o1;
#pragma unroll
                for (int rg = 0; rg < 4; ++rg)
                    dst[((size_t)(bi * H_ + hh) * S_ + (srow + rg)) * HD_ + hd] =
                        __float2bfloat16(acc[mi][nj][rg] + bv);
            }
        }
    }
}

// Flash attention — unchanged from R2 (verified: spill-free, dbuf DMA).
__global__ __launch_bounds__(256, 2)
void attn(const bf16* __restrict__ Qb, const bf16* __restrict__ Kb,
          const bf16* __restrict__ Vt, bf16* __restrict__ ctx)
{
    __shared__ __align__(16) char Ksm[2][64 * 256];
    __shared__ __align__(16) char Vsm[2][128 * 128];
    __shared__ __align__(16) char Pl[4 * 16 * 128];

    const int x = blockIdx.x;
    const int bh = blockIdx.y;
    const int u = (bh >> 3) & 1;
    const int qb = u ? x : (int)gridDim.x - 1 - x;
    const int b = bh >> 4, h = bh & 15;
    const int tid = threadIdx.x;
    const int wave = tid >> 6, lane = tid & 63;
    const int col = lane & 15, quad = lane >> 4;
    const int q0 = qb << 6;
    const int qg = q0 + wave * 16 + col;
    const float slope = exp2f(-0.5f * (float)(h + 1));
    const int sw = (col & 7) << 4;

    const bf16* Qp = Qb + ((size_t)bh * S_ + q0 + wave * 16) * HD_;
    s8v aq[4];
#pragma unroll
    for (int c = 0; c < 4; c++)
        aq[c] = *(const s8v*)(Qp + (size_t)col * HD_ + c * 32 + quad * 8);

    const f4v fzero = {0.f, 0.f, 0.f, 0.f};
    f4v o[8];
#pragma unroll
    for (int t = 0; t < 8; t++) o[t] = fzero;
    float m = -1e30f, l = 0.f;

    const bf16* Kbase = Kb + (size_t)bh * S_ * HD_;
    const bf16* Vbase = Vt + (size_t)bh * HD_ * S_;

    int ksrc[4], vsrc[4];
#pragma unroll
    for (int p = 0; p < 4; p++) {
        const int g = p * 256 + tid;
        const int kr = g >> 4, kb = g & 15;
        ksrc[p] = kr * HD_ + ((kb ^ (kr & 7)) << 3);
        const int vr = g >> 3, vb = g & 7;
        vsrc[p] = vr * S_ + ((vb ^ (vr & 7)) << 3);
    }
    const int ldst = tid << 4;

    {
        const bf16* Kp = Kbase;
        const bf16* Vp = Vbase;
#pragma unroll
        for (int p = 0; p < 4; p++) {
            gload_lds(Kp + ksrc[p], Ksm[0] + p * 4096 + ldst);
            gload_lds(Vp + vsrc[p], Vsm[0] + p * 4096 + ldst);
        }
    }
    __syncthreads();

    const int nkt = qb + 1;
    for (int kt = 0; kt < nkt; kt++) {
        const int cur = kt & 1;
        const int k0 = kt << 6;

        if (kt + 1 < nkt) {
            const bf16* Kp = Kbase + (size_t)(kt + 1) * 64 * HD_;
            const bf16* Vp = Vbase + (kt + 1) * 64;
            char* Kd = Ksm[cur ^ 1];
            char* Vd = Vsm[cur ^ 1];
#pragma unroll
            for (int p = 0; p < 4; p++) {
                gload_lds(Kp + ksrc[p], Kd + p * 4096 + ldst);
                gload_lds(Vp + vsrc[p], Vd + p * 4096 + ldst);
            }
        }
        const char* Kcur = Ksm[cur];
        const char* Vcur = Vsm[cur];

        f4v sc[4];
        __builtin_amdgcn_s_setprio(1);
#pragma unroll
        for (int st = 0; st < 4; st++) {
            sc[st] = fzero;
#pragma unroll
            for (int c = 0; c < 4; c++) {
                const s8v kf = *(const s8v*)(Kcur + (st * 16 + col) * 256 +
                                             ((c * 64 + quad * 16) ^ sw));
                sc[st] = mfma16(kf, aq[c], sc[st]);
            }
        }
        __builtin_amdgcn_s_setprio(0);

        float s[16];
        float mx = -1e30f;
#pragma unroll
        for (int st = 0; st < 4; st++)
#pragma unroll
            for (int r = 0; r < 4; r++) {
                const int key = k0 + st * 16 + (quad << 2) + r;
                float v = sc[st][r] * INV_NORM + slope * (float)key;
                v = (key > qg) ? -1e9f : v;
                s[st * 4 + r] = v;
                mx = fmaxf(mx, v);
            }
        mx = fmaxf(mx, __shfl_xor(mx, 16));
        mx = fmaxf(mx, __shfl_xor(mx, 32));
        const float nm = fmaxf(m, mx);
        float ps = 0.f;
#pragma unroll
        for (int i = 0; i < 16; i++) { s[i] = __expf(s[i] - nm); ps += s[i]; }
        ps += __shfl_xor(ps, 16);
        ps += __shfl_xor(ps, 32);
        const float alpha = __expf(m - nm);
        l = l * alpha + ps;
        m = nm;
#pragma unroll
        for (int t = 0; t < 8; t++) o[t] *= alpha;

        char* plw = Pl + wave * 2048 + col * 128;
#pragma unroll
        for (int st = 0; st < 4; st++) {
            union { ushort4 u4; bf16 hh[4]; } pk;
#pragma unroll
            for (int r = 0; r < 4; r++) pk.hh[r] = __float2bfloat16(s[st * 4 + r]);
            *(ushort4*)(plw + ((st * 32 + quad * 8) ^ sw)) = pk.u4;
        }
        const s8v pf0 = *(const s8v*)(plw + ((quad * 16) ^ sw));
        const s8v pf1 = *(const s8v*)(plw + ((64 + quad * 16) ^ sw));

        __builtin_amdgcn_s_setprio(1);
#pragma unroll
        for (int t = 0; t < 8; t++) {
            const s8v vf0 = *(const s8v*)(Vcur + (t * 16 + col) * 128 +
                                          ((quad * 16) ^ sw));
            o[t] = mfma16(vf0, pf0, o[t]);
            const s8v vf1 = *(const s8v*)(Vcur + (t * 16 + col) * 128 +
                                          ((64 + quad * 16) ^ sw));
            o[t] = mfma16(vf1, pf1, o[t]);
        }
        __builtin_amdgcn_s_setprio(0);

        __syncthreads();
    }

    const float rl = 1.0f / l;
#pragma unroll
    for (int t = 0; t < 8; t++) {
        union { ushort4 u4; bf16 hh[4]; } pk;
#pragma unroll
        for (int r = 0; r < 4; r++) pk.hh[r] = __float2bfloat16(o[t][r] * rl);
        *(ushort4*)&ctx[((size_t)(b * S_) + qg) * D_ + h * HD_ + t * 16 + (quad << 2)] =
            pk.u4;
    }
}

extern "C" void kernel_launch(void* const* d_in, const int* in_sizes, int n_in,
                              void* d_out, int out_size, void* d_ws, size_t ws_size,
                              hipStream_t stream)
{
    const float* hs    = (const float*)d_in[0];
    const float* resid = (const float*)d_in[1];
    // d_in[2] = alibi: analytic (slope = 2^(-0.5*(h+1)), score += slope*key)
    // d_in[3] = attention_mask: pure causal tril/-1e9, applied analytically
    const float* Wqkv  = (const float*)d_in[4];
    const float* bqkv  = (const float*)d_in[5];
    const float* Wd    = (const float*)d_in[6];
    const float* bd    = (const float*)d_in[7];
    float* out = (float*)d_out;

    const size_t seg  = (size_t)B_ * H_ * S_ * HD_;   // 8,388,608 elems
    const size_t nHS  = (size_t)B_ * S_ * D_;         // 8,388,608
    const size_t nWq  = (size_t)3 * D_ * D_;          // 12,582,912
    const size_t nWd  = (size_t)D_ * D_;              // 4,194,304
    bf16* Qbuf = (bf16*)d_ws;
    bf16* Kbuf = Qbuf + seg;
    bf16* Vtb  = Kbuf + seg;
    bf16* ctx  = Vtb + seg;
    bf16* hsb  = ctx + seg;
    bf16* Wqb  = hsb + nHS;
    bf16* Wdb  = Wqb + nWq;          // end: 58,720,256 bf16 = 117.4 MB

    cvt_f32_bf16<<<(int)(nHS / 4 + 255) / 256, 256, 0, stream>>>(hs, hsb, (int)(nHS / 4));
    cvt_f32_bf16<<<(int)(nWq / 4 + 255) / 256, 256, 0, stream>>>(Wqkv, Wqb, (int)(nWq / 4));
    cvt_f32_bf16<<<(int)(nWd / 4 + 255) / 256, 256, 0, stream>>>(Wd, Wdb, (int)(nWd / 4));

    gemm_qkv8<<<dim3(24, 16), 512, 0, stream>>>(hsb, Wqb, bqkv, Qbuf, Kbuf, Vtb);
    attn<<<dim3(32, 32), 256, 0, stream>>>(Qbuf, Kbuf, Vtb, ctx);
    gemm_bt<1><<<dim3(16, 32), 256, 0, stream>>>(ctx, Wdb, bd, resid,
                                                 nullptr, nullptr, nullptr, out, 2048);
}